// Round 1
// baseline (157.771 us; speedup 1.0000x reference)
//
#include <hip/hip_runtime.h>

// MemoryAugmentation: value[b,c] = softmax_m(x[b,c] . mem[m]) . mem
// B*C = 8192 rows, row length H*W = 7744 (= 1936 float4), M = 10 slots.
// One block of 256 threads handles R=4 consecutive rows.

#define RROWS   4
#define NM      10
#define NVEC    1936          // 7744 / 4 float4 per row
#define THREADS 256

__global__ void memaug_kernel(const float* __restrict__ x,
                              const float* __restrict__ mem,
                              float* __restrict__ out)
{
    const int tid  = threadIdx.x;
    const long r0  = (long)blockIdx.x * RROWS;   // first row of this block

    const float4* __restrict__ x4 = (const float4*)x;
    const float4* __restrict__ m4 = (const float4*)mem;
    float4* __restrict__ o4       = (float4*)out;

    // ---------------- Phase 1: scores[j][m] = x_row_j . mem_m ----------------
    float acc[RROWS][NM];
#pragma unroll
    for (int j = 0; j < RROWS; ++j)
#pragma unroll
        for (int m = 0; m < NM; ++m) acc[j][m] = 0.f;

    for (int iv = tid; iv < NVEC; iv += THREADS) {
        float4 xv[RROWS];
#pragma unroll
        for (int j = 0; j < RROWS; ++j)
            xv[j] = x4[(r0 + j) * NVEC + iv];
#pragma unroll
        for (int m = 0; m < NM; ++m) {
            const float4 mv = m4[(long)m * NVEC + iv];
#pragma unroll
            for (int j = 0; j < RROWS; ++j) {
                acc[j][m] += xv[j].x * mv.x + xv[j].y * mv.y
                           + xv[j].z * mv.z + xv[j].w * mv.w;
            }
        }
    }

    // Wave-level butterfly reduce (64 lanes)
#pragma unroll
    for (int j = 0; j < RROWS; ++j)
#pragma unroll
        for (int m = 0; m < NM; ++m) {
            float v = acc[j][m];
#pragma unroll
            for (int off = 32; off > 0; off >>= 1)
                v += __shfl_xor(v, off, 64);
            acc[j][m] = v;
        }

    __shared__ float red[4][RROWS][NM];   // per-wave partials
    __shared__ float prob[RROWS][NM];     // softmax probabilities

    const int wave = tid >> 6;
    const int lane = tid & 63;
    if (lane == 0) {
#pragma unroll
        for (int j = 0; j < RROWS; ++j)
#pragma unroll
            for (int m = 0; m < NM; ++m) red[wave][j][m] = acc[j][m];
    }
    __syncthreads();

    // ---------------- Softmax over m (threads 0..RROWS-1) ----------------
    if (tid < RROWS) {
        const int j = tid;
        float s[NM];
        float mx = -1e30f;
#pragma unroll
        for (int m = 0; m < NM; ++m) {
            s[m] = red[0][j][m] + red[1][j][m] + red[2][j][m] + red[3][j][m];
            mx = fmaxf(mx, s[m]);
        }
        float sum = 0.f;
#pragma unroll
        for (int m = 0; m < NM; ++m) { s[m] = expf(s[m] - mx); sum += s[m]; }
        const float inv = 1.f / sum;
#pragma unroll
        for (int m = 0; m < NM; ++m) prob[j][m] = s[m] * inv;
    }
    __syncthreads();

    float p[RROWS][NM];
#pragma unroll
    for (int j = 0; j < RROWS; ++j)
#pragma unroll
        for (int m = 0; m < NM; ++m) p[j][m] = prob[j][m];

    // ---------------- Phase 2: out_row_j = sum_m p[j][m] * mem_m ----------------
    for (int iv = tid; iv < NVEC; iv += THREADS) {
        float4 ov[RROWS];
#pragma unroll
        for (int j = 0; j < RROWS; ++j) ov[j] = make_float4(0.f, 0.f, 0.f, 0.f);
#pragma unroll
        for (int m = 0; m < NM; ++m) {
            const float4 mv = m4[(long)m * NVEC + iv];
#pragma unroll
            for (int j = 0; j < RROWS; ++j) {
                ov[j].x += p[j][m] * mv.x;
                ov[j].y += p[j][m] * mv.y;
                ov[j].z += p[j][m] * mv.z;
                ov[j].w += p[j][m] * mv.w;
            }
        }
#pragma unroll
        for (int j = 0; j < RROWS; ++j)
            o4[(r0 + j) * NVEC + iv] = ov[j];
    }
}

extern "C" void kernel_launch(void* const* d_in, const int* in_sizes, int n_in,
                              void* d_out, int out_size, void* d_ws, size_t ws_size,
                              hipStream_t stream) {
    const float* x   = (const float*)d_in[0];   // [32,256,88,88] f32
    const float* mem = (const float*)d_in[1];   // [10,88,88] f32
    float* out       = (float*)d_out;           // [32,256,88,88] f32

    const int rows   = 32 * 256;                // 8192
    const int blocks = rows / RROWS;            // 2048

    memaug_kernel<<<blocks, THREADS, 0, stream>>>(x, mem, out);
}

// Round 3
// 88.451 us; speedup vs baseline: 1.7837x; 1.7837x over previous
//
#include <hip/hip_runtime.h>

// MemoryAugmentation: value[b,c] = softmax_m(x[b,c] . mem[m]) . mem
// B*C = 8192 rows, row length H*W = 7744 (= 1936 float4), M = 10 slots.
// One block of 256 threads handles R=4 consecutive rows.
//
// R1/R2 changes vs R0:
//  - __launch_bounds__(256): R0 compiled at VGPR=64 (default assumes 1024-thr
//    blocks) -> loads serialized, latency-bound (VALUBusy 18%, HBM 27%).
//  - loads grouped before FMAs (x first, then mem) for max MLP.
//  - non-temporal stores for out (via native vector type; HIP float4 is a
//    class and rejected by __builtin_nontemporal_store).

#define RROWS   4
#define NM      10
#define NVEC    1936          // 7744 / 4 float4 per row
#define THREADS 256

typedef float f32x4 __attribute__((ext_vector_type(4)));

__global__ __launch_bounds__(THREADS)
void memaug_kernel(const float* __restrict__ x,
                   const float* __restrict__ mem,
                   float* __restrict__ out)
{
    const int tid = threadIdx.x;
    const long r0 = (long)blockIdx.x * RROWS;   // first row of this block

    const f32x4* __restrict__ m4  = (const f32x4*)mem;
    const f32x4* __restrict__ xr  = (const f32x4*)x + r0 * NVEC;
    f32x4* __restrict__ orow      = (f32x4*)out + r0 * NVEC;

    // ---------------- Phase 1: scores[j][m] = x_row_j . mem_m ----------------
    float acc[RROWS][NM];
#pragma unroll
    for (int j = 0; j < RROWS; ++j)
#pragma unroll
        for (int m = 0; m < NM; ++m) acc[j][m] = 0.f;

    for (int iv = tid; iv < NVEC; iv += THREADS) {
        // issue ALL loads first so they are concurrently outstanding
        f32x4 xv[RROWS];
#pragma unroll
        for (int j = 0; j < RROWS; ++j)
            xv[j] = xr[j * NVEC + iv];
        f32x4 mv[NM];
#pragma unroll
        for (int m = 0; m < NM; ++m)
            mv[m] = m4[m * NVEC + iv];
#pragma unroll
        for (int m = 0; m < NM; ++m) {
#pragma unroll
            for (int j = 0; j < RROWS; ++j) {
                acc[j][m] += xv[j].x * mv[m].x + xv[j].y * mv[m].y
                           + xv[j].z * mv[m].z + xv[j].w * mv[m].w;
            }
        }
    }

    // Wave-level butterfly reduce (64 lanes)
#pragma unroll
    for (int j = 0; j < RROWS; ++j)
#pragma unroll
        for (int m = 0; m < NM; ++m) {
            float v = acc[j][m];
#pragma unroll
            for (int off = 32; off > 0; off >>= 1)
                v += __shfl_xor(v, off, 64);
            acc[j][m] = v;
        }

    __shared__ float red[4][RROWS][NM];   // per-wave partials
    __shared__ float prob[RROWS][NM];     // softmax probabilities

    const int wave = tid >> 6;
    const int lane = tid & 63;
    if (lane == 0) {
#pragma unroll
        for (int j = 0; j < RROWS; ++j)
#pragma unroll
            for (int m = 0; m < NM; ++m) red[wave][j][m] = acc[j][m];
    }
    __syncthreads();

    // ---------------- Softmax over m (threads 0..RROWS-1) ----------------
    if (tid < RROWS) {
        const int j = tid;
        float s[NM];
        float mx = -1e30f;
#pragma unroll
        for (int m = 0; m < NM; ++m) {
            s[m] = red[0][j][m] + red[1][j][m] + red[2][j][m] + red[3][j][m];
            mx = fmaxf(mx, s[m]);
        }
        float sum = 0.f;
#pragma unroll
        for (int m = 0; m < NM; ++m) { s[m] = expf(s[m] - mx); sum += s[m]; }
        const float inv = 1.f / sum;
#pragma unroll
        for (int m = 0; m < NM; ++m) prob[j][m] = s[m] * inv;
    }
    __syncthreads();

    float p[RROWS][NM];
#pragma unroll
    for (int j = 0; j < RROWS; ++j)
#pragma unroll
        for (int m = 0; m < NM; ++m) p[j][m] = prob[j][m];

    // ---------------- Phase 2: out_row_j = sum_m p[j][m] * mem_m ----------------
    for (int iv = tid; iv < NVEC; iv += THREADS) {
        f32x4 mv[NM];
#pragma unroll
        for (int m = 0; m < NM; ++m)
            mv[m] = m4[m * NVEC + iv];

        f32x4 ov[RROWS];
#pragma unroll
        for (int j = 0; j < RROWS; ++j) ov[j] = (f32x4)(0.f);
#pragma unroll
        for (int m = 0; m < NM; ++m) {
#pragma unroll
            for (int j = 0; j < RROWS; ++j) {
                ov[j].x += p[j][m] * mv[m].x;
                ov[j].y += p[j][m] * mv[m].y;
                ov[j].z += p[j][m] * mv[m].z;
                ov[j].w += p[j][m] * mv[m].w;
            }
        }
#pragma unroll
        for (int j = 0; j < RROWS; ++j)
            __builtin_nontemporal_store(ov[j], &orow[j * NVEC + iv]);
    }
}

extern "C" void kernel_launch(void* const* d_in, const int* in_sizes, int n_in,
                              void* d_out, int out_size, void* d_ws, size_t ws_size,
                              hipStream_t stream) {
    const float* x   = (const float*)d_in[0];   // [32,256,88,88] f32
    const float* mem = (const float*)d_in[1];   // [10,88,88] f32
    float* out       = (float*)d_out;           // [32,256,88,88] f32

    const int rows   = 32 * 256;                // 8192
    const int blocks = rows / RROWS;            // 2048

    memaug_kernel<<<blocks, THREADS, 0, stream>>>(x, mem, out);
}